// Round 3
// baseline (41.261 us; speedup 1.0000x reference)
//
#include <hip/hip_runtime.h>
#include <hip/hip_bf16.h>

typedef __attribute__((ext_vector_type(8))) short bf16x8;
typedef __attribute__((ext_vector_type(4))) float f32x4;

#define NB 8192
#define NS 8

__device__ __forceinline__ unsigned short f2bf(float f) {
  union { float f; unsigned int u; } v; v.f = f;
  unsigned int r = v.u + 0x7FFFu + ((v.u >> 16) & 1u);
  return (unsigned short)(r >> 16);
}

// Full 64-lane max-reduce over lane bits 4..5 (row groups), pure VALU.
// After this every lane holds max over {l, l^16, l^32, l^48}.
__device__ __forceinline__ float rowgroup_max(float mx) {
  float y = mx;
  asm("" : "+v"(y));  // pin copy to its own VGPR
  asm("v_permlane32_swap_b32 %0, %1" : "+v"(mx), "+v"(y));
  mx = fmaxf(mx, y);
  y = mx;
  asm("" : "+v"(y));
  asm("v_permlane16_swap_b32 %0, %1" : "+v"(mx), "+v"(y));
  return fmaxf(mx, y);
}

// Prep: W2 (64x1024 f32) -> bf16 in MFMA B-fragment order; Wc = [W_emb;b_emb] @ W1[0:64,:]
__global__ __launch_bounds__(256) void prep_kernel(
    const float* __restrict__ W2, const float* __restrict__ W_emb,
    const float* __restrict__ b_emb, const float* __restrict__ W1,
    unsigned short* __restrict__ w2f, float* __restrict__ wc) {
  int tid = blockIdx.x * 256 + threadIdx.x;
  if (tid < 8192) {
    int lane = tid & 63;
    int ks = (tid >> 6) & 1;
    int nt = tid >> 7;
    int col = nt * 16 + (lane & 15);
    int k0 = ks * 32 + (lane >> 4) * 8;
    bf16x8 pk;
#pragma unroll
    for (int e = 0; e < 8; ++e)
      pk[e] = (short)f2bf(W2[(k0 + e) * 1024 + col]);
    *(bf16x8*)(w2f + tid * 8) = pk;
  } else if (tid < 8192 + 192) {
    int t2 = tid - 8192;
    int c = t2 >> 6, k = t2 & 63;
    float s = 0.f;
    for (int e = 0; e < 64; ++e) {
      float src = (c < 2) ? W_emb[c * 64 + e] : b_emb[e];
      s += src * W1[e * 64 + k];
    }
    wc[t2] = s;  // wc[0][k], wc[1][k], cbe[k]
  }
}

// Main: one block per group, 8 waves. A = relu(rel@Wc + hW) built in LDS in
// fragment order, then 256x1024x64 bf16 MFMA GEMM; pooling fully in-register
// via permlane swaps; packed full-wave 256B stores.
__global__ __launch_bounds__(512, 4) void pool_kernel(
    const float* __restrict__ in_xy, const float* __restrict__ h_states,
    const float* __restrict__ W1, const float* __restrict__ b1,
    const float* __restrict__ b2, const unsigned short* __restrict__ w2f,
    const float* __restrict__ wc, float* __restrict__ out) {
  __shared__ bf16x8 Afrag[2048];     // 32 KB, fragment-ordered A (256x64 bf16)
  __shared__ float hW[16 * 68];      // padded rows to spread banks
  __shared__ float exy[32];          // x[0:16], y[16:32]
  const int g = blockIdx.x;
  const int t = threadIdx.x;
  const int lane = t & 63;
  const int wv = t >> 6;

  if (t < 32) {
    int p = t & 15;
    exy[t] = in_xy[((NS - 1) * NB + g * 16 + p) * 2 + (t >> 4)];
  }

  // hW[j][k] = b1[k] + cbe[k] + sum_e h[g*16+j][e] * W1[64+e][k]; 2 rows/thread
  {
    int k = t & 63;
    int j0 = t >> 6;  // 0..7, wave-uniform
    const float* hbase = h_states + g * 16 * 64;
    float a0 = 0.f, a1 = 0.f;
    for (int e = 0; e < 64; ++e) {
      float w = W1[(64 + e) * 64 + k];
      a0 += hbase[j0 * 64 + e] * w;
      a1 += hbase[(j0 + 8) * 64 + e] * w;
    }
    float bb = b1[k] + wc[128 + k];
    hW[j0 * 68 + k] = a0 + bb;
    hW[(j0 + 8) * 68 + k] = a1 + bb;
  }

  // B fragments resident in VGPRs (8 ntiles/wave) + per-lane bias for the
  // two packed store columns (wv*128 + ub*64 + lane)
  bf16x8 bfr[8][2];
#pragma unroll
  for (int u = 0; u < 8; ++u) {
    int nt = wv * 8 + u;
    bfr[u][0] = *(const bf16x8*)(w2f + ((nt * 2 + 0) * 64 + lane) * 8);
    bfr[u][1] = *(const bf16x8*)(w2f + ((nt * 2 + 1) * 64 + lane) * 8);
  }
  float b2a = b2[wv * 128 + lane];
  float b2b = b2[wv * 128 + 64 + lane];
  __syncthreads();

  // A build: thread t writes granules t + 512*c (fixed j=t&15, fixed k-chunk, m=(t>>7)+4c)
  {
    int j = t & 15;
    int kc = (t >> 4) & 3;
    int ks = (t >> 6) & 1;
    int k0 = ks * 32 + kc * 8;
    int mb = t >> 7;  // 0..3
    float w0[8], w1[8], hv[8];
#pragma unroll
    for (int e = 0; e < 8; ++e) {
      w0[e] = wc[k0 + e];
      w1[e] = wc[64 + k0 + e];
      hv[e] = hW[j * 68 + k0 + e];
    }
    float exj = exy[j], eyj = exy[16 + j];
#pragma unroll
    for (int c = 0; c < 4; ++c) {
      int m = mb + 4 * c;  // i index
      float rx = exj - exy[m];
      float ry = eyj - exy[16 + m];
      bf16x8 pk;
#pragma unroll
      for (int e = 0; e < 8; ++e) {
        float v = rx * w0[e] + ry * w1[e] + hv[e];
        v = fmaxf(v, 0.f);
        pk[e] = (short)f2bf(v);
      }
      Afrag[t + 512 * c] = pk;
    }
  }
  __syncthreads();

  // GEMM + fused pool. Wave wv owns 128 cols (ntiles wv*8 .. wv*8+7).
  const int grp = lane >> 4;
  const int obase = (g * 16) * 1024 + wv * 128 + lane;
  for (int m = 0; m < 16; ++m) {
    bf16x8 a0 = Afrag[(m * 2 + 0) * 64 + lane];
    bf16x8 a1 = Afrag[(m * 2 + 1) * 64 + lane];
    f32x4 acc[8];
#pragma unroll
    for (int u = 0; u < 8; ++u) {
      f32x4 z = {0.f, 0.f, 0.f, 0.f};
      acc[u] = __builtin_amdgcn_mfma_f32_16x16x32_bf16(a0, bfr[u][0], z, 0, 0, 0);
    }
#pragma unroll
    for (int u = 0; u < 8; ++u)
      acc[u] = __builtin_amdgcn_mfma_f32_16x16x32_bf16(a1, bfr[u][1], acc[u], 0, 0, 0);
    // pool: in-lane max over 4 regs, then permlane reduce over row groups
    float r[8];
#pragma unroll
    for (int u = 0; u < 8; ++u) {
      float mx = fmaxf(fmaxf(acc[u][0], acc[u][1]), fmaxf(acc[u][2], acc[u][3]));
      r[u] = rowgroup_max(mx);
    }
    // pack: lane l takes u = ub*4 + (l>>4), col = ub*64 + l; full-wave 256B stores
    float v0 = (grp == 0) ? r[0] : (grp == 1) ? r[1] : (grp == 2) ? r[2] : r[3];
    float v1 = (grp == 0) ? r[4] : (grp == 1) ? r[5] : (grp == 2) ? r[6] : r[7];
    out[obase + m * 1024] = fmaxf(v0 + b2a, 0.f);
    out[obase + m * 1024 + 64] = fmaxf(v1 + b2b, 0.f);
  }
}

extern "C" void kernel_launch(void* const* d_in, const int* in_sizes, int n_in,
                              void* d_out, int out_size, void* d_ws, size_t ws_size,
                              hipStream_t stream) {
  const float* in_xy = (const float*)d_in[0];
  const float* h_states = (const float*)d_in[2];
  const float* W_emb = (const float*)d_in[4];
  const float* b_emb = (const float*)d_in[5];
  const float* W1 = (const float*)d_in[6];
  const float* b1 = (const float*)d_in[7];
  const float* W2 = (const float*)d_in[8];
  const float* b2 = (const float*)d_in[9];
  float* out = (float*)d_out;

  unsigned short* w2f = (unsigned short*)d_ws;            // 131072 B
  float* wc = (float*)((char*)d_ws + 131072);             // 192 f32

  prep_kernel<<<33, 256, 0, stream>>>(W2, W_emb, b_emb, W1, w2f, wc);
  pool_kernel<<<512, 512, 0, stream>>>(in_xy, h_states, W1, b1, b2, w2f, wc, out);
}

// Round 4
// 33.824 us; speedup vs baseline: 1.2199x; 1.2199x over previous
//
#include <hip/hip_runtime.h>
#include <hip/hip_bf16.h>

typedef __attribute__((ext_vector_type(8))) short bf16x8;
typedef __attribute__((ext_vector_type(4))) float f32x4;
typedef __attribute__((ext_vector_type(2))) float f32x2;

#define NB 8192
#define NS 8

__device__ __forceinline__ unsigned short f2bf(float f) {
  union { float f; unsigned int u; } v; v.f = f;
  unsigned int r = v.u + 0x7FFFu + ((v.u >> 16) & 1u);
  return (unsigned short)(r >> 16);
}

// Prep: W2 (64x1024 f32) -> bf16 in MFMA B-fragment order; Wc = [W_emb;b_emb] @ W1[0:64,:]
__global__ __launch_bounds__(256) void prep_kernel(
    const float* __restrict__ W2, const float* __restrict__ W_emb,
    const float* __restrict__ b_emb, const float* __restrict__ W1,
    unsigned short* __restrict__ w2f, float* __restrict__ wc) {
  int tid = blockIdx.x * 256 + threadIdx.x;
  if (tid < 8192) {
    int lane = tid & 63;
    int ks = (tid >> 6) & 1;
    int nt = tid >> 7;
    int col = nt * 16 + (lane & 15);
    int k0 = ks * 32 + (lane >> 4) * 8;
    bf16x8 pk;
#pragma unroll
    for (int e = 0; e < 8; ++e)
      pk[e] = (short)f2bf(W2[(k0 + e) * 1024 + col]);
    *(bf16x8*)(w2f + tid * 8) = pk;
  } else if (tid < 8192 + 192) {
    int t2 = tid - 8192;
    int c = t2 >> 6, k = t2 & 63;
    float s = 0.f;
    for (int e = 0; e < 64; ++e) {
      float src = (c < 2) ? W_emb[c * 64 + e] : b_emb[e];
      s += src * W1[e * 64 + k];
    }
    wc[t2] = s;  // wc[0][k], wc[1][k], cbe[k]
  }
}

// Main: one block per group, 8 waves. A = relu(rel@Wc + hW) built in LDS in
// fragment order, then 256x1024x64 bf16 MFMA GEMM. Pool epilogue uses a
// per-wave LDS transpose whose flush is DEFERRED one m-iteration so the
// LDS write->read round trip is off the critical path.
__global__ __launch_bounds__(512, 4) void pool_kernel(
    const float* __restrict__ in_xy, const float* __restrict__ h_states,
    const float* __restrict__ W1, const float* __restrict__ b1,
    const float* __restrict__ b2, const unsigned short* __restrict__ w2f,
    const float* __restrict__ wc, float* __restrict__ out) {
  __shared__ bf16x8 Afrag[2048];     // 32 KB, fragment-ordered A (256x64 bf16)
  __shared__ float hW[16 * 68];      // padded rows to spread banks
  __shared__ float exy[32];          // x[0:16], y[16:32]
  __shared__ float pm[8][512];       // per-wave pool scratch, swizzled
  const int g = blockIdx.x;
  const int t = threadIdx.x;
  const int lane = t & 63;
  const int wv = t >> 6;

  if (t < 32) {
    int p = t & 15;
    exy[t] = in_xy[((NS - 1) * NB + g * 16 + p) * 2 + (t >> 4)];
  }

  // hW[j][k] = b1[k] + cbe[k] + sum_e h[g*16+j][e] * W1[64+e][k]; 2 rows/thread
  {
    int k = t & 63;
    int j0 = t >> 6;  // 0..7, wave-uniform
    const float* hbase = h_states + g * 16 * 64;
    float a0 = 0.f, a1 = 0.f;
    for (int e = 0; e < 64; ++e) {
      float w = W1[(64 + e) * 64 + k];
      a0 += hbase[j0 * 64 + e] * w;
      a1 += hbase[(j0 + 8) * 64 + e] * w;
    }
    float bb = b1[k] + wc[128 + k];
    hW[j0 * 68 + k] = a0 + bb;
    hW[(j0 + 8) * 68 + k] = a1 + bb;
  }

  // B fragments resident in VGPRs (8 ntiles/wave) + bias pair for epilogue
  bf16x8 bfr[8][2];
#pragma unroll
  for (int u = 0; u < 8; ++u) {
    int nt = wv * 8 + u;
    bfr[u][0] = *(const bf16x8*)(w2f + ((nt * 2 + 0) * 64 + lane) * 8);
    bfr[u][1] = *(const bf16x8*)(w2f + ((nt * 2 + 1) * 64 + lane) * 8);
  }
  f32x2 b2v = *(const f32x2*)(b2 + wv * 128 + lane * 2);
  __syncthreads();

  // A build: thread t writes granules t + 512*c (fixed j=t&15, fixed k-chunk, m=(t>>7)+4c)
  {
    int j = t & 15;
    int kc = (t >> 4) & 3;
    int ks = (t >> 6) & 1;
    int k0 = ks * 32 + kc * 8;
    int mb = t >> 7;  // 0..3
    float w0[8], w1[8], hv[8];
#pragma unroll
    for (int e = 0; e < 8; ++e) {
      w0[e] = wc[k0 + e];
      w1[e] = wc[64 + k0 + e];
      hv[e] = hW[j * 68 + k0 + e];
    }
    float exj = exy[j], eyj = exy[16 + j];
#pragma unroll
    for (int c = 0; c < 4; ++c) {
      int m = mb + 4 * c;  // i index
      float rx = exj - exy[m];
      float ry = eyj - exy[16 + m];
      bf16x8 pk;
#pragma unroll
      for (int e = 0; e < 8; ++e) {
        float v = rx * w0[e] + ry * w1[e] + hv[e];
        v = fmaxf(v, 0.f);
        pk[e] = (short)f2bf(v);
      }
      Afrag[t + 512 * c] = pk;
    }
  }
  __syncthreads();

  // GEMM + fused pool. Wave wv owns 128 cols (ntiles wv*8 .. wv*8+7).
  float* pmw = &pm[wv][0];
  const int r = lane >> 4, cc = lane & 15;            // pm write coords
  const int ru = lane >> 3, rc = (2 * lane) & 15;     // pm read coords
  const int obase = (g * 16) * 1024 + wv * 128 + lane * 2;
  const bf16x8* ap = Afrag + lane;

  bf16x8 a0 = ap[0];
  bf16x8 a1 = ap[64];
  for (int m = 0; m < 16; ++m) {
    // Issue transpose reads of the PREVIOUS iteration's maxima BEFORE this
    // iteration's writes (same wave, program order preserved on the
    // aliasing LDS buffer). Garbage at m==0, unused.
    f32x2 v0 = *(const f32x2*)&pmw[0 * 128 + (((ru ^ 0) << 4) | rc)];
    f32x2 v1 = *(const f32x2*)&pmw[1 * 128 + (((ru ^ 1) << 4) | rc)];
    f32x2 v2 = *(const f32x2*)&pmw[2 * 128 + (((ru ^ 2) << 4) | rc)];
    f32x2 v3 = *(const f32x2*)&pmw[3 * 128 + (((ru ^ 3) << 4) | rc)];

    // u-half 0: MFMA + in-lane max + pm write
    {
      f32x4 acc[4];
      __builtin_amdgcn_s_setprio(1);
#pragma unroll
      for (int u = 0; u < 4; ++u) {
        f32x4 z = {0.f, 0.f, 0.f, 0.f};
        acc[u] = __builtin_amdgcn_mfma_f32_16x16x32_bf16(a0, bfr[u][0], z, 0, 0, 0);
      }
#pragma unroll
      for (int u = 0; u < 4; ++u)
        acc[u] = __builtin_amdgcn_mfma_f32_16x16x32_bf16(a1, bfr[u][1], acc[u], 0, 0, 0);
      __builtin_amdgcn_s_setprio(0);
#pragma unroll
      for (int u = 0; u < 4; ++u) {
        float mx = fmaxf(fmaxf(acc[u][0], acc[u][1]), fmaxf(acc[u][2], acc[u][3]));
        pmw[r * 128 + (((u ^ r) << 4) | cc)] = mx;
      }
    }
    // u-half 1: MFMA + in-lane max + pm write; prefetch next a-frags after last use
    {
      f32x4 acc[4];
      __builtin_amdgcn_s_setprio(1);
#pragma unroll
      for (int u = 0; u < 4; ++u) {
        f32x4 z = {0.f, 0.f, 0.f, 0.f};
        acc[u] = __builtin_amdgcn_mfma_f32_16x16x32_bf16(a0, bfr[u + 4][0], z, 0, 0, 0);
      }
#pragma unroll
      for (int u = 0; u < 4; ++u)
        acc[u] = __builtin_amdgcn_mfma_f32_16x16x32_bf16(a1, bfr[u + 4][1], acc[u], 0, 0, 0);
      __builtin_amdgcn_s_setprio(0);
      int mn = (m + 1) & 15;  // m=15 wraps harmlessly
      a0 = ap[mn * 128];
      a1 = ap[mn * 128 + 64];
#pragma unroll
      for (int u = 0; u < 4; ++u) {
        float mx = fmaxf(fmaxf(acc[u][0], acc[u][1]), fmaxf(acc[u][2], acc[u][3]));
        pmw[r * 128 + ((((u + 4) ^ r) << 4) | cc)] = mx;
      }
    }
    // flush previous iteration (reads issued at top of this iteration)
    if (m > 0) {
      float o0 = fmaxf(fmaxf(v0[0], v1[0]), fmaxf(v2[0], v3[0]));
      float o1 = fmaxf(fmaxf(v0[1], v1[1]), fmaxf(v2[1], v3[1]));
      f32x2 res;
      res[0] = fmaxf(o0 + b2v[0], 0.f);
      res[1] = fmaxf(o1 + b2v[1], 0.f);
      *(f32x2*)(out + obase + (m - 1) * 1024) = res;
    }
  }
  // final flush (m = 15)
  {
    f32x2 v0 = *(const f32x2*)&pmw[0 * 128 + (((ru ^ 0) << 4) | rc)];
    f32x2 v1 = *(const f32x2*)&pmw[1 * 128 + (((ru ^ 1) << 4) | rc)];
    f32x2 v2 = *(const f32x2*)&pmw[2 * 128 + (((ru ^ 2) << 4) | rc)];
    f32x2 v3 = *(const f32x2*)&pmw[3 * 128 + (((ru ^ 3) << 4) | rc)];
    float o0 = fmaxf(fmaxf(v0[0], v1[0]), fmaxf(v2[0], v3[0]));
    float o1 = fmaxf(fmaxf(v0[1], v1[1]), fmaxf(v2[1], v3[1]));
    f32x2 res;
    res[0] = fmaxf(o0 + b2v[0], 0.f);
    res[1] = fmaxf(o1 + b2v[1], 0.f);
    *(f32x2*)(out + obase + 15 * 1024) = res;
  }
}

extern "C" void kernel_launch(void* const* d_in, const int* in_sizes, int n_in,
                              void* d_out, int out_size, void* d_ws, size_t ws_size,
                              hipStream_t stream) {
  const float* in_xy = (const float*)d_in[0];
  const float* h_states = (const float*)d_in[2];
  const float* W_emb = (const float*)d_in[4];
  const float* b_emb = (const float*)d_in[5];
  const float* W1 = (const float*)d_in[6];
  const float* b1 = (const float*)d_in[7];
  const float* W2 = (const float*)d_in[8];
  const float* b2 = (const float*)d_in[9];
  float* out = (float*)d_out;

  unsigned short* w2f = (unsigned short*)d_ws;            // 131072 B
  float* wc = (float*)((char*)d_ws + 131072);             // 192 f32

  prep_kernel<<<33, 256, 0, stream>>>(W2, W_emb, b_emb, W1, w2f, wc);
  pool_kernel<<<512, 512, 0, stream>>>(in_xy, h_states, W1, b1, b2, w2f, wc, out);
}

// Round 5
// 31.179 us; speedup vs baseline: 1.3233x; 1.0848x over previous
//
#include <hip/hip_runtime.h>
#include <hip/hip_bf16.h>

typedef __attribute__((ext_vector_type(8))) short bf16x8;
typedef __attribute__((ext_vector_type(4))) float f32x4;

#define NB 8192
#define NS 8

__device__ __forceinline__ unsigned short f2bf(float f) {
  union { float f; unsigned int u; } v; v.f = f;
  unsigned int r = v.u + 0x7FFFu + ((v.u >> 16) & 1u);
  return (unsigned short)(r >> 16);
}

// Prep: W2 (64x1024 f32) -> bf16 in MFMA B-fragment order; Wc = [W_emb;b_emb] @ W1[0:64,:]
__global__ __launch_bounds__(256) void prep_kernel(
    const float* __restrict__ W2, const float* __restrict__ W_emb,
    const float* __restrict__ b_emb, const float* __restrict__ W1,
    unsigned short* __restrict__ w2f, float* __restrict__ wc) {
  int tid = blockIdx.x * 256 + threadIdx.x;
  if (tid < 8192) {
    int lane = tid & 63;
    int ks = (tid >> 6) & 1;
    int nt = tid >> 7;
    int col = nt * 16 + (lane & 15);
    int k0 = ks * 32 + (lane >> 4) * 8;
    bf16x8 pk;
#pragma unroll
    for (int e = 0; e < 8; ++e)
      pk[e] = (short)f2bf(W2[(k0 + e) * 1024 + col]);
    *(bf16x8*)(w2f + tid * 8) = pk;
  } else if (tid < 8192 + 192) {
    int t2 = tid - 8192;
    int c = t2 >> 6, k = t2 & 63;
    float s = 0.f;
    for (int e = 0; e < 64; ++e) {
      float src = (c < 2) ? W_emb[c * 64 + e] : b_emb[e];
      s += src * W1[e * 64 + k];
    }
    wc[t2] = s;  // wc[0][k], wc[1][k], cbe[k]
  }
}

// Main: one block per group, 8 waves. M-tiles are {16 i's, fixed j}: iterate
// tiles over j, so the max-pool (over j) is a register-elementwise fmax on the
// accumulator fragments -- no cross-lane reduction, no epilogue LDS, one store
// pass at the end. Two ntile passes (4 each) keep VGPR under the 128 cap.
__global__ __launch_bounds__(512, 4) void pool_kernel(
    const float* __restrict__ in_xy, const float* __restrict__ h_states,
    const float* __restrict__ W1, const float* __restrict__ b1,
    const float* __restrict__ b2, const unsigned short* __restrict__ w2f,
    const float* __restrict__ wc, float* __restrict__ out) {
  __shared__ bf16x8 Afrag[2048];     // 32 KB, fragment-ordered A (256x64 bf16), tile=j
  __shared__ float hW[16 * 68];      // padded rows to spread banks
  __shared__ float exy[32];          // x[0:16], y[16:32]
  const int g = blockIdx.x;
  const int t = threadIdx.x;
  const int lane = t & 63;
  const int wv = t >> 6;

  if (t < 32) {
    int p = t & 15;
    exy[t] = in_xy[((NS - 1) * NB + g * 16 + p) * 2 + (t >> 4)];
  }

  // hW[j][k] = b1[k] + cbe[k] + sum_e h[g*16+j][e] * W1[64+e][k]; 2 rows/thread
  {
    int k = t & 63;
    int j0 = t >> 6;  // 0..7, wave-uniform
    const float* hbase = h_states + g * 16 * 64;
    float a0 = 0.f, a1 = 0.f;
    for (int e = 0; e < 64; ++e) {
      float w = W1[(64 + e) * 64 + k];
      a0 += hbase[j0 * 64 + e] * w;
      a1 += hbase[(j0 + 8) * 64 + e] * w;
    }
    float bb = b1[k] + wc[128 + k];
    hW[j0 * 68 + k] = a0 + bb;
    hW[(j0 + 8) * 68 + k] = a1 + bb;
  }

  // Per-lane bias for the epilogue store columns
  float b2v[8];
#pragma unroll
  for (int u = 0; u < 8; ++u) b2v[u] = b2[wv * 128 + u * 16 + (lane & 15)];
  __syncthreads();

  // A build: thread t -> row i=t&15, k-chunk from bits 4..6, tile j=(t>>7)+4c.
  // A_j[i,k] = relu(rel(i,j)x*wc0[k] + rel(i,j)y*wc1[k] + hW[j][k])
  {
    int i = t & 15;
    int kc = (t >> 4) & 3;
    int ks = (t >> 6) & 1;
    int k0 = ks * 32 + kc * 8;
    int jb = t >> 7;  // 0..3
    float w0[8], w1[8];
#pragma unroll
    for (int e = 0; e < 8; ++e) {
      w0[e] = wc[k0 + e];
      w1[e] = wc[64 + k0 + e];
    }
    float exi = exy[i], eyi = exy[16 + i];
#pragma unroll
    for (int c = 0; c < 4; ++c) {
      int j = jb + 4 * c;  // tile index
      float rx = exy[j] - exi;
      float ry = exy[16 + j] - eyi;
      const f32x4* hp = (const f32x4*)&hW[j * 68 + k0];
      f32x4 h0 = hp[0], h1 = hp[1];
      float hv[8] = {h0[0], h0[1], h0[2], h0[3], h1[0], h1[1], h1[2], h1[3]};
      bf16x8 pk;
#pragma unroll
      for (int e = 0; e < 8; ++e) {
        float v = fmaf(rx, w0[e], fmaf(ry, w1[e], hv[e]));
        v = fmaxf(v, 0.f);
        pk[e] = (short)f2bf(v);
      }
      Afrag[t + 512 * c] = pk;
    }
  }
  __syncthreads();

  // GEMM + register pooling. Wave wv owns 128 cols; two passes of 4 ntiles.
  const int col = lane & 15;
  const int rowoff = (g * 16 + (lane >> 4) * 4) * 1024 + wv * 128 + col;
  const bf16x8* ap = Afrag + lane;
#pragma unroll
  for (int pass = 0; pass < 2; ++pass) {
    bf16x8 bfr[4][2];
#pragma unroll
    for (int u = 0; u < 4; ++u) {
      int nt = wv * 8 + pass * 4 + u;
      bfr[u][0] = *(const bf16x8*)(w2f + ((nt * 2 + 0) * 64 + lane) * 8);
      bfr[u][1] = *(const bf16x8*)(w2f + ((nt * 2 + 1) * 64 + lane) * 8);
    }
    f32x4 pool[4];
#pragma unroll
    for (int u = 0; u < 4; ++u) pool[u] = (f32x4){-3.4e38f, -3.4e38f, -3.4e38f, -3.4e38f};

    bf16x8 a0 = ap[0];
    bf16x8 a1 = ap[64];
    for (int j = 0; j < 16; ++j) {
      f32x4 acc[4];
      __builtin_amdgcn_s_setprio(1);
#pragma unroll
      for (int u = 0; u < 4; ++u) {
        f32x4 z = {0.f, 0.f, 0.f, 0.f};
        acc[u] = __builtin_amdgcn_mfma_f32_16x16x32_bf16(a0, bfr[u][0], z, 0, 0, 0);
      }
#pragma unroll
      for (int u = 0; u < 4; ++u)
        acc[u] = __builtin_amdgcn_mfma_f32_16x16x32_bf16(a1, bfr[u][1], acc[u], 0, 0, 0);
      __builtin_amdgcn_s_setprio(0);
      int jn = (j + 1) & 15;  // j=15 wraps harmlessly
      a0 = ap[jn * 128];
      a1 = ap[jn * 128 + 64];
#pragma unroll
      for (int u = 0; u < 4; ++u) {
#pragma unroll
        for (int r = 0; r < 4; ++r) pool[u][r] = fmaxf(pool[u][r], acc[u][r]);
      }
    }
    // Epilogue: bias + relu + store. Rows = i (pool output rows).
#pragma unroll
    for (int u = 0; u < 4; ++u) {
      float bb = b2v[pass * 4 + u];
      int cbase = rowoff + (pass * 4 + u) * 16;
#pragma unroll
      for (int r = 0; r < 4; ++r)
        out[cbase + r * 1024] = fmaxf(pool[u][r] + bb, 0.f);
    }
  }
}

extern "C" void kernel_launch(void* const* d_in, const int* in_sizes, int n_in,
                              void* d_out, int out_size, void* d_ws, size_t ws_size,
                              hipStream_t stream) {
  const float* in_xy = (const float*)d_in[0];
  const float* h_states = (const float*)d_in[2];
  const float* W_emb = (const float*)d_in[4];
  const float* b_emb = (const float*)d_in[5];
  const float* W1 = (const float*)d_in[6];
  const float* b1 = (const float*)d_in[7];
  const float* W2 = (const float*)d_in[8];
  const float* b2 = (const float*)d_in[9];
  float* out = (float*)d_out;

  unsigned short* w2f = (unsigned short*)d_ws;            // 131072 B
  float* wc = (float*)((char*)d_ws + 131072);             // 192 f32

  prep_kernel<<<33, 256, 0, stream>>>(W2, W_emb, b_emb, W1, w2f, wc);
  pool_kernel<<<512, 512, 0, stream>>>(in_xy, h_states, W1, b1, b2, w2f, wc, out);
}

// Round 6
// 29.821 us; speedup vs baseline: 1.3836x; 1.0455x over previous
//
#include <hip/hip_runtime.h>
#include <hip/hip_bf16.h>

typedef __attribute__((ext_vector_type(8))) short bf16x8;
typedef __attribute__((ext_vector_type(4))) float f32x4;

#define NB 8192
#define NS 8

__device__ __forceinline__ unsigned short f2bf(float f) {
  union { float f; unsigned int u; } v; v.f = f;
  unsigned int r = v.u + 0x7FFFu + ((v.u >> 16) & 1u);
  return (unsigned short)(r >> 16);
}

// prep1: W2 -> bf16 B-fragments (w2f); Wc = [W_emb;b_emb]@W1a (wc);
//        W1b (rows 64..127) -> bf16 B-fragments (w1bf)
__global__ __launch_bounds__(256) void prep_kernel(
    const float* __restrict__ W2, const float* __restrict__ W_emb,
    const float* __restrict__ b_emb, const float* __restrict__ W1,
    unsigned short* __restrict__ w2f, float* __restrict__ wc,
    unsigned short* __restrict__ w1bf) {
  int tid = blockIdx.x * 256 + threadIdx.x;
  if (tid < 8192) {
    int lane = tid & 63;
    int ks = (tid >> 6) & 1;
    int nt = tid >> 7;
    int col = nt * 16 + (lane & 15);
    int k0 = ks * 32 + (lane >> 4) * 8;
    bf16x8 pk;
#pragma unroll
    for (int e = 0; e < 8; ++e)
      pk[e] = (short)f2bf(W2[(k0 + e) * 1024 + col]);
    *(bf16x8*)(w2f + tid * 8) = pk;
  } else if (tid < 8192 + 192) {
    int t2 = tid - 8192;
    int c = t2 >> 6, k = t2 & 63;
    float s = 0.f;
    for (int e = 0; e < 64; ++e) {
      float src = (c < 2) ? W_emb[c * 64 + e] : b_emb[e];
      s += src * W1[e * 64 + k];
    }
    wc[t2] = s;  // wc0[k], wc1[k], cbe[k]
  } else if (tid < 8192 + 192 + 512) {
    int q = tid - 8384;
    int lane = q & 63;
    int fr = q >> 6;          // nt*2 + ks
    int nt = fr >> 1, ks = fr & 1;
    int col = nt * 16 + (lane & 15);
    int e0 = ks * 32 + (lane >> 4) * 8;
    bf16x8 pk;
#pragma unroll
    for (int e = 0; e < 8; ++e)
      pk[e] = (short)f2bf(W1[(64 + e0 + e) * 64 + col]);
    *(bf16x8*)(w1bf + q * 8) = pk;
  }
}

// prep2: hW[b][k] = b1[k] + cbe[k] + h[b]@W1b  via one-wave MFMA blocks.
__global__ __launch_bounds__(64) void hw_kernel(
    const float* __restrict__ h_states, const float* __restrict__ b1,
    const float* __restrict__ wc, const unsigned short* __restrict__ w1bf,
    float* __restrict__ hW) {
  const int lane = threadIdx.x;
  const int b = blockIdx.x;
  const int row = b * 16 + (lane & 15);
  const int k0 = (lane >> 4) * 8;
  const float* hp = h_states + row * 64 + k0;
  bf16x8 a0, a1;
#pragma unroll
  for (int e = 0; e < 8; ++e) {
    a0[e] = (short)f2bf(hp[e]);
    a1[e] = (short)f2bf(hp[e + 32]);
  }
#pragma unroll
  for (int nt = 0; nt < 4; ++nt) {
    bf16x8 bf0 = *(const bf16x8*)(w1bf + ((nt * 2 + 0) * 64 + lane) * 8);
    bf16x8 bf1 = *(const bf16x8*)(w1bf + ((nt * 2 + 1) * 64 + lane) * 8);
    f32x4 z = {0.f, 0.f, 0.f, 0.f};
    f32x4 acc = __builtin_amdgcn_mfma_f32_16x16x32_bf16(a0, bf0, z, 0, 0, 0);
    acc = __builtin_amdgcn_mfma_f32_16x16x32_bf16(a1, bf1, acc, 0, 0, 0);
    int col = nt * 16 + (lane & 15);
    float bb = b1[col] + wc[128 + col];
#pragma unroll
    for (int r = 0; r < 4; ++r)
      hW[(b * 16 + (lane >> 4) * 4 + r) * 64 + col] = acc[r] + bb;
  }
}

// pool: block = (group, col-half). 256 threads (4 waves), 4 blocks/CU for
// phase staggering. A built in LDS fragment order from precomputed hW;
// 256x512x64 MFMA GEMM per block with register max-pooling over j-tiles.
__global__ __launch_bounds__(256, 4) void pool_kernel(
    const float* __restrict__ in_xy, const float* __restrict__ b2,
    const unsigned short* __restrict__ w2f, const float* __restrict__ wc,
    const float* __restrict__ hW, float* __restrict__ out) {
  __shared__ bf16x8 Afrag[2048];  // 32 KB, fragment-ordered A (256x64 bf16), tile=j
  __shared__ float exy[32];       // x[0:16], y[16:32]
  const int g = blockIdx.x >> 1;
  const int half = blockIdx.x & 1;
  const int t = threadIdx.x;
  const int lane = t & 63;
  const int wv = t >> 6;  // 0..3

  if (t < 32) {
    int p = t & 15;
    exy[t] = in_xy[((NS - 1) * NB + g * 16 + p) * 2 + (t >> 4)];
  }

  // bias for epilogue columns (independent of exy)
  float b2v[8];
#pragma unroll
  for (int u = 0; u < 8; ++u)
    b2v[u] = b2[half * 512 + wv * 128 + u * 16 + (lane & 15)];

  // Per-thread k-slice constants (global, L2-hot)
  const int i = t & 15;
  const int kc = (t >> 4) & 3;
  const int ks = (t >> 6) & 1;
  const int k0 = ks * 32 + kc * 8;
  float w0[8], w1[8];
#pragma unroll
  for (int e = 0; e < 8; ++e) {
    w0[e] = wc[k0 + e];
    w1[e] = wc[64 + k0 + e];
  }
  __syncthreads();

  // A build: granule G = t + 256c -> lane=G&63, ks bit, j = (t>>7)+2c.
  // A_j[i,k] = relu(rel(i,j)x*wc0[k] + rel(i,j)y*wc1[k] + hW[g*16+j][k])
  {
    float exi = exy[i], eyi = exy[16 + i];
#pragma unroll
    for (int c = 0; c < 8; ++c) {
      int j = (t >> 7) + 2 * c;
      float rx = exy[j] - exi;
      float ry = exy[16 + j] - eyi;
      const f32x4* hp = (const f32x4*)(hW + (g * 16 + j) * 64 + k0);
      f32x4 h0 = hp[0], h1 = hp[1];
      float hv[8] = {h0[0], h0[1], h0[2], h0[3], h1[0], h1[1], h1[2], h1[3]};
      bf16x8 pk;
#pragma unroll
      for (int e = 0; e < 8; ++e) {
        float v = fmaf(rx, w0[e], fmaf(ry, w1[e], hv[e]));
        v = fmaxf(v, 0.f);
        pk[e] = (short)f2bf(v);
      }
      Afrag[t + 256 * c] = pk;
    }
  }
  __syncthreads();

  // GEMM + register pooling. Wave wv owns 128 cols; two passes of 4 ntiles.
  const int rowbase = (g * 16 + (lane >> 4) * 4) * 1024 + half * 512 + wv * 128 + (lane & 15);
  const bf16x8* ap = Afrag + lane;
#pragma unroll
  for (int pass = 0; pass < 2; ++pass) {
    bf16x8 bfr[4][2];
#pragma unroll
    for (int u = 0; u < 4; ++u) {
      int nt = half * 32 + wv * 8 + pass * 4 + u;
      bfr[u][0] = *(const bf16x8*)(w2f + ((nt * 2 + 0) * 64 + lane) * 8);
      bfr[u][1] = *(const bf16x8*)(w2f + ((nt * 2 + 1) * 64 + lane) * 8);
    }
    f32x4 pool[4];
#pragma unroll
    for (int u = 0; u < 4; ++u) pool[u] = (f32x4){-3.4e38f, -3.4e38f, -3.4e38f, -3.4e38f};

#pragma unroll 4
    for (int j = 0; j < 16; ++j) {
      bf16x8 a0 = ap[j * 128];
      bf16x8 a1 = ap[j * 128 + 64];
      f32x4 acc[4];
      __builtin_amdgcn_s_setprio(1);
#pragma unroll
      for (int u = 0; u < 4; ++u) {
        f32x4 z = {0.f, 0.f, 0.f, 0.f};
        acc[u] = __builtin_amdgcn_mfma_f32_16x16x32_bf16(a0, bfr[u][0], z, 0, 0, 0);
      }
#pragma unroll
      for (int u = 0; u < 4; ++u)
        acc[u] = __builtin_amdgcn_mfma_f32_16x16x32_bf16(a1, bfr[u][1], acc[u], 0, 0, 0);
      __builtin_amdgcn_s_setprio(0);
#pragma unroll
      for (int u = 0; u < 4; ++u) {
#pragma unroll
        for (int r = 0; r < 4; ++r) pool[u][r] = fmaxf(pool[u][r], acc[u][r]);
      }
    }
#pragma unroll
    for (int u = 0; u < 4; ++u) {
      float bb = b2v[pass * 4 + u];
#pragma unroll
      for (int r = 0; r < 4; ++r)
        out[rowbase + r * 1024 + (pass * 4 + u) * 16] = fmaxf(pool[u][r] + bb, 0.f);
    }
  }
}

extern "C" void kernel_launch(void* const* d_in, const int* in_sizes, int n_in,
                              void* d_out, int out_size, void* d_ws, size_t ws_size,
                              hipStream_t stream) {
  const float* in_xy = (const float*)d_in[0];
  const float* h_states = (const float*)d_in[2];
  const float* W_emb = (const float*)d_in[4];
  const float* b_emb = (const float*)d_in[5];
  const float* W1 = (const float*)d_in[6];
  const float* b1 = (const float*)d_in[7];
  const float* W2 = (const float*)d_in[8];
  const float* b2 = (const float*)d_in[9];
  float* out = (float*)d_out;

  unsigned short* w2f = (unsigned short*)d_ws;                  // 128 KB @ 0
  float* wc = (float*)((char*)d_ws + 131072);                   // 768 B
  unsigned short* w1bf = (unsigned short*)((char*)d_ws + 132096);  // 8 KB
  float* hW = (float*)((char*)d_ws + 262144);                   // 2 MB

  prep_kernel<<<35, 256, 0, stream>>>(W2, W_emb, b_emb, W1, w2f, wc, w1bf);
  hw_kernel<<<512, 64, 0, stream>>>(h_states, b1, wc, w1bf, hW);
  pool_kernel<<<1024, 256, 0, stream>>>(in_xy, b2, w2f, wc, hW, out);
}

// Round 7
// 28.225 us; speedup vs baseline: 1.4618x; 1.0565x over previous
//
#include <hip/hip_runtime.h>
#include <hip/hip_bf16.h>

typedef __attribute__((ext_vector_type(8))) short bf16x8;
typedef __attribute__((ext_vector_type(4))) float f32x4;

#define NB 8192
#define NS 8

__device__ __forceinline__ unsigned short f2bf(float f) {
  union { float f; unsigned int u; } v; v.f = f;
  unsigned int r = v.u + 0x7FFFu + ((v.u >> 16) & 1u);
  return (unsigned short)(r >> 16);
}

// prep: W2 -> bf16 B-fragments (w2f); Wc = [W_emb;b_emb]@W1a (wc);
//       W1b (rows 64..127) -> bf16 B-fragments (w1bf)
__global__ __launch_bounds__(256) void prep_kernel(
    const float* __restrict__ W2, const float* __restrict__ W_emb,
    const float* __restrict__ b_emb, const float* __restrict__ W1,
    unsigned short* __restrict__ w2f, float* __restrict__ wc,
    unsigned short* __restrict__ w1bf) {
  int tid = blockIdx.x * 256 + threadIdx.x;
  if (tid < 8192) {
    int lane = tid & 63;
    int ks = (tid >> 6) & 1;
    int nt = tid >> 7;
    int col = nt * 16 + (lane & 15);
    int k0 = ks * 32 + (lane >> 4) * 8;
    bf16x8 pk;
#pragma unroll
    for (int e = 0; e < 8; ++e)
      pk[e] = (short)f2bf(W2[(k0 + e) * 1024 + col]);
    *(bf16x8*)(w2f + tid * 8) = pk;
  } else if (tid < 8192 + 192) {
    int t2 = tid - 8192;
    int c = t2 >> 6, k = t2 & 63;
    float s = 0.f;
    for (int e = 0; e < 64; ++e) {
      float src = (c < 2) ? W_emb[c * 64 + e] : b_emb[e];
      s += src * W1[e * 64 + k];
    }
    wc[t2] = s;  // wc0[k], wc1[k], cbe[k]
  } else if (tid < 8192 + 192 + 512) {
    int q = tid - 8384;
    int lane = q & 63;
    int fr = q >> 6;          // nt*2 + ks
    int nt = fr >> 1, ks = fr & 1;
    int col = nt * 16 + (lane & 15);
    int e0 = ks * 32 + (lane >> 4) * 8;
    bf16x8 pk;
#pragma unroll
    for (int e = 0; e < 8; ++e)
      pk[e] = (short)f2bf(W1[(64 + e0 + e) * 64 + col]);
    *(bf16x8*)(w1bf + q * 8) = pk;
  }
}

// pool: block = (group, col-half), 256 threads (4 waves), 4 blocks/CU.
// Phase 0: fused hW tile (wave wv -> ntile wv, 2 MFMAs) into LDS.
// Phase 1: A (tile=j) built into LDS in fragment order.
// Phase 2: 256x512x64 MFMA GEMM, register max-pool over j with a 2-deep
//          accumulator rotation so pool-fmax consumes the PREVIOUS iteration's
//          MFMA results (latency hidden behind current MFMA cluster).
__global__ __launch_bounds__(256, 4) void pool_kernel(
    const float* __restrict__ in_xy, const float* __restrict__ h_states,
    const float* __restrict__ b1, const float* __restrict__ b2,
    const unsigned short* __restrict__ w2f, const float* __restrict__ wc,
    const unsigned short* __restrict__ w1bf, float* __restrict__ out) {
  __shared__ bf16x8 Afrag[2048];  // 32 KB, fragment-ordered A (256x64 bf16), tile=j
  __shared__ float hWs[16][72];   // hW tile (pad 72 -> 16B-aligned rows)
  __shared__ float exy[32];       // x[0:16], y[16:32]
  const int g = blockIdx.x >> 1;
  const int half = blockIdx.x & 1;
  const int t = threadIdx.x;
  const int lane = t & 63;
  const int wv = t >> 6;  // 0..3

  if (t < 32) {
    int p = t & 15;
    exy[t] = in_xy[((NS - 1) * NB + g * 16 + p) * 2 + (t >> 4)];
  }

  // Phase 0: hW[j][k] = b1[k] + cbe[k] + h[g*16+j] @ W1b. Wave wv -> ntile wv.
  {
    const int row = g * 16 + (lane & 15);
    const int e0 = (lane >> 4) * 8;
    const float* hp = h_states + row * 64 + e0;
    bf16x8 ha0, ha1;
#pragma unroll
    for (int e = 0; e < 8; ++e) {
      ha0[e] = (short)f2bf(hp[e]);
      ha1[e] = (short)f2bf(hp[e + 32]);
    }
    bf16x8 bf0 = *(const bf16x8*)(w1bf + ((wv * 2 + 0) * 64 + lane) * 8);
    bf16x8 bf1 = *(const bf16x8*)(w1bf + ((wv * 2 + 1) * 64 + lane) * 8);
    f32x4 z = {0.f, 0.f, 0.f, 0.f};
    f32x4 acc = __builtin_amdgcn_mfma_f32_16x16x32_bf16(ha0, bf0, z, 0, 0, 0);
    acc = __builtin_amdgcn_mfma_f32_16x16x32_bf16(ha1, bf1, acc, 0, 0, 0);
    int col = wv * 16 + (lane & 15);
    float bb = b1[col] + wc[128 + col];
#pragma unroll
    for (int r = 0; r < 4; ++r)
      hWs[(lane >> 4) * 4 + r][col] = acc[r] + bb;
  }

  // epilogue bias + per-thread k-slice constants (global, L2-hot; no LDS dep)
  float b2v[8];
#pragma unroll
  for (int u = 0; u < 8; ++u)
    b2v[u] = b2[half * 512 + wv * 128 + u * 16 + (lane & 15)];
  const int i = t & 15;
  const int k0 = ((t >> 6) & 1) * 32 + ((t >> 4) & 3) * 8;
  float w0[8], w1[8];
#pragma unroll
  for (int e = 0; e < 8; ++e) {
    w0[e] = wc[k0 + e];
    w1[e] = wc[64 + k0 + e];
  }
  __syncthreads();

  // Phase 1: A build. Granule G = t + 256c -> j = (t>>7)+2c.
  // A_j[i,k] = relu(rel(i,j)x*wc0[k] + rel(i,j)y*wc1[k] + hW[j][k])
  {
    float exi = exy[i], eyi = exy[16 + i];
#pragma unroll
    for (int c = 0; c < 8; ++c) {
      int j = (t >> 7) + 2 * c;
      float rx = exy[j] - exi;
      float ry = exy[16 + j] - eyi;
      const f32x4* hp2 = (const f32x4*)&hWs[j][k0];
      f32x4 h0 = hp2[0], h1 = hp2[1];
      float hv[8] = {h0[0], h0[1], h0[2], h0[3], h1[0], h1[1], h1[2], h1[3]};
      bf16x8 pk;
#pragma unroll
      for (int e = 0; e < 8; ++e) {
        float v = fmaf(rx, w0[e], fmaf(ry, w1[e], hv[e]));
        v = fmaxf(v, 0.f);
        pk[e] = (short)f2bf(v);
      }
      Afrag[t + 256 * c] = pk;
    }
  }
  __syncthreads();

  // Phase 2: GEMM + register pooling, 2 passes of 4 ntiles, acc double-buffer.
  const int rowbase = (g * 16 + (lane >> 4) * 4) * 1024 + half * 512 + wv * 128 + (lane & 15);
  const bf16x8* ap = Afrag + lane;
  const f32x4 NEGINF = {-3.4e38f, -3.4e38f, -3.4e38f, -3.4e38f};
#pragma unroll
  for (int pass = 0; pass < 2; ++pass) {
    bf16x8 bfr[4][2];
#pragma unroll
    for (int u = 0; u < 4; ++u) {
      int nt = half * 32 + wv * 8 + pass * 4 + u;
      bfr[u][0] = *(const bf16x8*)(w2f + ((nt * 2 + 0) * 64 + lane) * 8);
      bfr[u][1] = *(const bf16x8*)(w2f + ((nt * 2 + 1) * 64 + lane) * 8);
    }
    f32x4 pool[4], accB[4];
#pragma unroll
    for (int u = 0; u < 4; ++u) { pool[u] = NEGINF; accB[u] = NEGINF; }

    bf16x8 a0 = ap[0];
    bf16x8 a1 = ap[64];
#pragma unroll
    for (int jj = 0; jj < 16; jj += 2) {
      // even iter -> accA; pool-fmax consumes accB (iter jj-1; -inf at jj=0)
      f32x4 accA[4];
      __builtin_amdgcn_s_setprio(1);
#pragma unroll
      for (int u = 0; u < 4; ++u) {
        f32x4 z = {0.f, 0.f, 0.f, 0.f};
        accA[u] = __builtin_amdgcn_mfma_f32_16x16x32_bf16(a0, bfr[u][0], z, 0, 0, 0);
      }
#pragma unroll
      for (int u = 0; u < 4; ++u)
        accA[u] = __builtin_amdgcn_mfma_f32_16x16x32_bf16(a1, bfr[u][1], accA[u], 0, 0, 0);
      __builtin_amdgcn_s_setprio(0);
      bf16x8 c0 = ap[(jj + 1) * 128];
      bf16x8 c1 = ap[(jj + 1) * 128 + 64];
#pragma unroll
      for (int u = 0; u < 4; ++u)
#pragma unroll
        for (int r = 0; r < 4; ++r) pool[u][r] = fmaxf(pool[u][r], accB[u][r]);

      // odd iter -> accB; pool-fmax consumes accA
      __builtin_amdgcn_s_setprio(1);
#pragma unroll
      for (int u = 0; u < 4; ++u) {
        f32x4 z = {0.f, 0.f, 0.f, 0.f};
        accB[u] = __builtin_amdgcn_mfma_f32_16x16x32_bf16(c0, bfr[u][0], z, 0, 0, 0);
      }
#pragma unroll
      for (int u = 0; u < 4; ++u)
        accB[u] = __builtin_amdgcn_mfma_f32_16x16x32_bf16(c1, bfr[u][1], accB[u], 0, 0, 0);
      __builtin_amdgcn_s_setprio(0);
      int jn = (jj + 2) & 15;  // wrap harmless
      a0 = ap[jn * 128];
      a1 = ap[jn * 128 + 64];
#pragma unroll
      for (int u = 0; u < 4; ++u)
#pragma unroll
        for (int r = 0; r < 4; ++r) pool[u][r] = fmaxf(pool[u][r], accA[u][r]);
    }
    // tail: accB holds j=15
#pragma unroll
    for (int u = 0; u < 4; ++u)
#pragma unroll
      for (int r = 0; r < 4; ++r) pool[u][r] = fmaxf(pool[u][r], accB[u][r]);

#pragma unroll
    for (int u = 0; u < 4; ++u) {
      float bb = b2v[pass * 4 + u];
#pragma unroll
      for (int r = 0; r < 4; ++r)
        out[rowbase + r * 1024 + (pass * 4 + u) * 16] = fmaxf(pool[u][r] + bb, 0.f);
    }
  }
}

extern "C" void kernel_launch(void* const* d_in, const int* in_sizes, int n_in,
                              void* d_out, int out_size, void* d_ws, size_t ws_size,
                              hipStream_t stream) {
  const float* in_xy = (const float*)d_in[0];
  const float* h_states = (const float*)d_in[2];
  const float* W_emb = (const float*)d_in[4];
  const float* b_emb = (const float*)d_in[5];
  const float* W1 = (const float*)d_in[6];
  const float* b1 = (const float*)d_in[7];
  const float* W2 = (const float*)d_in[8];
  const float* b2 = (const float*)d_in[9];
  float* out = (float*)d_out;

  unsigned short* w2f = (unsigned short*)d_ws;                     // 128 KB @ 0
  float* wc = (float*)((char*)d_ws + 131072);                      // 768 B
  unsigned short* w1bf = (unsigned short*)((char*)d_ws + 132096);  // 8 KB

  prep_kernel<<<35, 256, 0, stream>>>(W2, W_emb, b_emb, W1, w2f, wc, w1bf);
  pool_kernel<<<1024, 256, 0, stream>>>(in_xy, h_states, b1, b2, w2f, wc, w1bf, out);
}